// Round 3
// baseline (264.816 us; speedup 1.0000x reference)
//
#include <hip/hip_runtime.h>

// out[b,h,w,c] = x[b,h,w,c] * mask[h,w,c], ALL FLOAT32 (threshold arithmetic
// in R1/R2 proved _any_bf16=false: thr = 0.02*absmax exactly, no bf16 floor).
// mask[h,w,c]=0 iff ANY batch's time strip (ts[b]<=h<ts[b]+8, trand[b,h-ts,w,c]<0.15)
//           or ANY batch's freq strip (fs[b]<=w<fs[b]+8, frand[b,h,w-fs,c]<0.15) hits;
// prod_b(1 - {0,1}) == NOT OR. Mask is batch-independent ([H,W,C]).
constexpr int B_ = 64, H_ = 512, W_ = 256, C_ = 4, L_ = 8;
constexpr int WC   = W_ * C_;      // 1024 floats per h-row
constexpr int HWC  = H_ * WC;      // 524288
constexpr int ROWS = 2;            // h-rows per block
constexpr int BCH  = 8;            // batches per block

__global__ __launch_bounds__(256)
void mask_apply_f32(const float* __restrict__ x,
                    const float* __restrict__ trand,
                    const float* __restrict__ frand,
                    const int* __restrict__ tstart,
                    const int* __restrict__ fstart,
                    float* __restrict__ out) {
    __shared__ int flagw[ROWS * WC / 4];            // 512 words = 2048 flag bytes
    __shared__ int ts_s[B_], fs_s[B_];
    unsigned char* flags = (unsigned char*)flagw;

    const int t  = threadIdx.x;                     // 0..255
    const int h0 = blockIdx.x * ROWS;               // 0..510
    const int b0 = blockIdx.y * BCH;

    flagw[2 * t] = 0; flagw[2 * t + 1] = 0;
    if (t < B_) { ts_s[t] = tstart[t]; fs_s[t] = fstart[t]; }
    __syncthreads();

    // --- time hits: ~1 qualifying batch per row on average
    for (int b = 0; b < B_; ++b) {
        int ts = ts_s[b];
#pragma unroll
        for (int r = 0; r < ROWS; ++r) {
            int l = h0 + r - ts;
            if ((unsigned)l < (unsigned)L_) {
                const float* row = trand + (b * L_ + l) * WC;   // [B,L,W,C]
#pragma unroll
                for (int k = 0; k < 4; ++k) {
                    int i = t * 4 + k;              // 256 thr x 4 = 1024
                    if (row[i] < 0.15f) flags[r * WC + i] = 1;
                }
            }
        }
    }

    // --- freq hits: 32 lanes per batch (128B contiguous frand reads), 8 batches/pass
    {
        int bsub = t >> 5, lane = t & 31;
        int l = lane >> 2, c = lane & 3;            // 8 w-offsets x 4 channels
        for (int bb = 0; bb < B_; bb += 8) {
            int b  = bb + bsub;
            int fs = fs_s[b];
#pragma unroll
            for (int r = 0; r < ROWS; ++r) {
                // frand layout [B,H,L,C]: ((b*H + h)*8 + l)*4 + c
                float v = frand[(b * H_ + h0 + r) * (L_ * C_) + l * C_ + c];
                if (v < 0.15f) flags[r * WC + (fs + l) * C_ + c] = 1;  // same-value race benign
            }
        }
    }
    __syncthreads();

    // --- apply: float4 per lane per row; flag word t covers floats t*4..t*4+3
    const unsigned fw0 = (unsigned)flagw[t];        // row h0
    const unsigned fw1 = (unsigned)flagw[256 + t];  // row h0+1
    for (int bi = 0; bi < BCH; ++bi) {
        int base = (b0 + bi) * HWC + h0 * WC;       // max ~33.5M elements, fits int
        float4 v0 = ((const float4*)(x + base))[t];
        float4 v1 = ((const float4*)(x + base + WC))[t];
        if (fw0) {
            if (fw0 & 0xffu)       v0.x = 0.f;
            if (fw0 & 0xff00u)     v0.y = 0.f;
            if (fw0 & 0xff0000u)   v0.z = 0.f;
            if (fw0 & 0xff000000u) v0.w = 0.f;
        }
        if (fw1) {
            if (fw1 & 0xffu)       v1.x = 0.f;
            if (fw1 & 0xff00u)     v1.y = 0.f;
            if (fw1 & 0xff0000u)   v1.z = 0.f;
            if (fw1 & 0xff000000u) v1.w = 0.f;
        }
        ((float4*)(out + base))[t]      = v0;
        ((float4*)(out + base + WC))[t] = v1;
    }
}

extern "C" void kernel_launch(void* const* d_in, const int* in_sizes, int n_in,
                              void* d_out, int out_size, void* d_ws, size_t ws_size,
                              hipStream_t stream) {
    const float* x  = (const float*)d_in[0];
    const float* tr = (const float*)d_in[1];
    const float* fr = (const float*)d_in[2];
    const int*   ts = (const int*)d_in[3];
    const int*   fs = (const int*)d_in[4];
    float* out = (float*)d_out;

    dim3 grid(H_ / ROWS, B_ / BCH);                 // (256, 8) = 2048 blocks
    mask_apply_f32<<<grid, 256, 0, stream>>>(x, tr, fr, ts, fs, out);
}

// Round 4
// 260.356 us; speedup vs baseline: 1.0171x; 1.0171x over previous
//
#include <hip/hip_runtime.h>

// out[b,h,w,c] = x[b,h,w,c] * mask[h,w,c], ALL FLOAT32.
// mask[h,w,c]=0 iff ANY batch's time strip (ts[b]<=h<ts[b]+8, trand[b,h-ts,w,c]<0.15)
//           or ANY batch's freq strip (fs[b]<=w<fs[b]+8, frand[b,h,w-fs,c]<0.15) hits;
// prod_b(1 - {0,1}) == NOT OR. Mask is batch-independent ([H,W,C]).
//
// R3 post-mortem: VGPR_Count=12 -> compiler serialized the apply loop
// (load -> vmcnt(0) -> store per iteration), 2.03 TB/s = 25% peak, latency-bound.
// R4: preload all 16 float4 into registers at kernel entry (MLP=16 loads/thread
// in flight), overlap mask build with load latency, then mask+store.
constexpr int B_ = 64, H_ = 512, W_ = 256, C_ = 4, L_ = 8;
constexpr int WC   = W_ * C_;      // 1024 floats per h-row
constexpr int HWC  = H_ * WC;      // 524288 floats per batch
constexpr int ROWS = 2;            // h-rows per block
constexpr int BCH  = 8;            // batches per block

__global__ __launch_bounds__(256)
void mask_apply_f32(const float* __restrict__ x,
                    const float* __restrict__ trand,
                    const float* __restrict__ frand,
                    const int* __restrict__ tstart,
                    const int* __restrict__ fstart,
                    float* __restrict__ out) {
    __shared__ int flagw[ROWS * WC / 4];            // 512 words = 2048 flag bytes
    __shared__ int ts_s[B_], fs_s[B_];
    unsigned char* flags = (unsigned char*)flagw;

    const int t  = threadIdx.x;                     // 0..255
    const int h0 = blockIdx.x * ROWS;               // 0..510
    const int b0 = blockIdx.y * BCH;

    // ---- issue ALL x-loads first: 16 independent float4 loads per thread,
    // in flight while the mask is built (compiler waits only at first use).
    float4 v[ROWS * BCH];
    const float4* xp = (const float4*)(x + h0 * WC) + t;   // this thread's slot
#pragma unroll
    for (int bi = 0; bi < BCH; ++bi) {
        int bb = (b0 + bi) * (HWC / 4);             // float4 offset, < 8.4M
        v[2 * bi]     = xp[bb];                     // row h0
        v[2 * bi + 1] = xp[bb + WC / 4];            // row h0+1
    }

    flagw[2 * t] = 0; flagw[2 * t + 1] = 0;
    if (t < B_) { ts_s[t] = tstart[t]; fs_s[t] = fstart[t]; }
    __syncthreads();

    // --- time hits: ~2 qualifying (b,row) pairs per block on average
    for (int b = 0; b < B_; ++b) {
        int ts = ts_s[b];
#pragma unroll
        for (int r = 0; r < ROWS; ++r) {
            int l = h0 + r - ts;
            if ((unsigned)l < (unsigned)L_) {
                const float* row = trand + (b * L_ + l) * WC;   // [B,L,W,C]
#pragma unroll
                for (int k = 0; k < 4; ++k) {
                    int i = t * 4 + k;              // 256 thr x 4 = 1024
                    if (row[i] < 0.15f) flags[r * WC + i] = 1;
                }
            }
        }
    }

    // --- freq hits: 32 lanes per batch (128B contiguous frand reads), 8 batches/pass
    {
        int bsub = t >> 5, lane = t & 31;
        int l = lane >> 2, c = lane & 3;            // 8 w-offsets x 4 channels
        for (int bb = 0; bb < B_; bb += 8) {
            int b  = bb + bsub;
            int fs = fs_s[b];
#pragma unroll
            for (int r = 0; r < ROWS; ++r) {
                // frand layout [B,H,L,C]: ((b*H + h)*8 + l)*4 + c
                float vf = frand[(b * H_ + h0 + r) * (L_ * C_) + l * C_ + c];
                if (vf < 0.15f) flags[r * WC + (fs + l) * C_ + c] = 1;  // same-value race ok
            }
        }
    }
    __syncthreads();

    // --- mask + store: flag word t covers floats t*4..t*4+3 of each row
    const unsigned fw0 = (unsigned)flagw[t];        // row h0
    const unsigned fw1 = (unsigned)flagw[256 + t];  // row h0+1
    float4* op = (float4*)(out + h0 * WC) + t;
#pragma unroll
    for (int bi = 0; bi < BCH; ++bi) {
        float4 v0 = v[2 * bi], v1 = v[2 * bi + 1];
        if (fw0) {
            if (fw0 & 0xffu)       v0.x = 0.f;
            if (fw0 & 0xff00u)     v0.y = 0.f;
            if (fw0 & 0xff0000u)   v0.z = 0.f;
            if (fw0 & 0xff000000u) v0.w = 0.f;
        }
        if (fw1) {
            if (fw1 & 0xffu)       v1.x = 0.f;
            if (fw1 & 0xff00u)     v1.y = 0.f;
            if (fw1 & 0xff0000u)   v1.z = 0.f;
            if (fw1 & 0xff000000u) v1.w = 0.f;
        }
        int bb = (b0 + bi) * (HWC / 4);
        op[bb]          = v0;
        op[bb + WC / 4] = v1;
    }
}

extern "C" void kernel_launch(void* const* d_in, const int* in_sizes, int n_in,
                              void* d_out, int out_size, void* d_ws, size_t ws_size,
                              hipStream_t stream) {
    const float* x  = (const float*)d_in[0];
    const float* tr = (const float*)d_in[1];
    const float* fr = (const float*)d_in[2];
    const int*   ts = (const int*)d_in[3];
    const int*   fs = (const int*)d_in[4];
    float* out = (float*)d_out;

    dim3 grid(H_ / ROWS, B_ / BCH);                 // (256, 8) = 2048 blocks
    mask_apply_f32<<<grid, 256, 0, stream>>>(x, tr, fr, ts, fs, out);
}

// Round 5
// 251.576 us; speedup vs baseline: 1.0526x; 1.0349x over previous
//
#include <hip/hip_runtime.h>

// out[b,h,w,c] = x[b,h,w,c] * mask[h,w,c], ALL FLOAT32.
// mask[h,w,c]=0 iff ANY batch's time strip (ts[b]<=h<ts[b]+8, trand[b,h-ts,w,c]<0.15)
//           or ANY batch's freq strip (fs[b]<=w<fs[b]+8, frand[b,h,w-fs,c]<0.15) hits.
//
// R4 post-mortem: fused kernel stuck at 2.17 TB/s — compiler sinks preloads past
// barriers (VGPR 40 not 64+), and vmcnt FIFO waits drain stores too -> serial
// load->wait->store chain. R5: two kernels. build_mask writes the 2MB f32 mask
// to d_ws; apply is a barrier-free pure-streaming multiply (mask L2-resident).
constexpr int B_ = 64, H_ = 512, W_ = 256, C_ = 4, L_ = 8;
constexpr int WC    = W_ * C_;       // 1024 floats per h-row
constexpr int HWC   = H_ * WC;       // 524288 floats (2 MB mask)
constexpr int MWC4  = HWC / 4;       // 131072 float4 in mask
constexpr long long N4 = 8388608LL;  // total float4 in x/out

// ---- kernel 1: mask build. Thread t of block h owns (h, w=t, c=0..3). ----
__global__ __launch_bounds__(256)
void build_mask(const float* __restrict__ trand, const float* __restrict__ frand,
                const int* __restrict__ tstart, const int* __restrict__ fstart,
                float* __restrict__ mask) {
    __shared__ int ts_s[B_], fs_s[B_];
    const int t = threadIdx.x;                      // == w
    const int h = blockIdx.x;
    if (t < B_) { ts_s[t] = tstart[t]; fs_s[t] = fstart[t]; }
    __syncthreads();

    float m0 = 1.f, m1 = 1.f, m2 = 1.f, m3 = 1.f;
    for (int b = 0; b < B_; ++b) {
        int lt = h - ts_s[b];
        if ((unsigned)lt < (unsigned)L_) {          // time strip covers this h
            // trand [B,L,W,C]: ((b*8+lt)*256 + w)*4, 16B-aligned
            float4 v = *(const float4*)(trand + ((b * L_ + lt) * W_ + t) * C_);
            if (v.x < 0.15f) m0 = 0.f;
            if (v.y < 0.15f) m1 = 0.f;
            if (v.z < 0.15f) m2 = 0.f;
            if (v.w < 0.15f) m3 = 0.f;
        }
        int lw = t - fs_s[b];
        if ((unsigned)lw < (unsigned)L_) {          // freq strip covers this w
            // frand [B,H,L,C]: ((b*512+h)*8 + lw)*4, 16B-aligned
            float4 v = *(const float4*)(frand + ((b * H_ + h) * L_ + lw) * C_);
            if (v.x < 0.15f) m0 = 0.f;
            if (v.y < 0.15f) m1 = 0.f;
            if (v.z < 0.15f) m2 = 0.f;
            if (v.w < 0.15f) m3 = 0.f;
        }
    }
    *(float4*)(mask + (h * W_ + t) * C_) = make_float4(m0, m1, m2, m3);
}

// ---- kernel 2: pure streaming multiply; no LDS, no barriers. ----
// 8192 blocks x 256 thr x 4 float4. Mask (2MB) is L2-resident.
__global__ __launch_bounds__(256)
void apply_mask(const float4* __restrict__ x4, const float4* __restrict__ m4,
                float4* __restrict__ out4) {
    const int base = blockIdx.x * 1024 + threadIdx.x;
    float4 a0 = x4[base];
    float4 a1 = x4[base + 256];
    float4 a2 = x4[base + 512];
    float4 a3 = x4[base + 768];
    float4 b0 = m4[ base         & (MWC4 - 1)];
    float4 b1 = m4[(base +  256) & (MWC4 - 1)];
    float4 b2 = m4[(base +  512) & (MWC4 - 1)];
    float4 b3 = m4[(base +  768) & (MWC4 - 1)];
    a0.x *= b0.x; a0.y *= b0.y; a0.z *= b0.z; a0.w *= b0.w;
    a1.x *= b1.x; a1.y *= b1.y; a1.z *= b1.z; a1.w *= b1.w;
    a2.x *= b2.x; a2.y *= b2.y; a2.z *= b2.z; a2.w *= b2.w;
    a3.x *= b3.x; a3.y *= b3.y; a3.z *= b3.z; a3.w *= b3.w;
    out4[base]       = a0;
    out4[base + 256] = a1;
    out4[base + 512] = a2;
    out4[base + 768] = a3;
}

// ---- fallback (proven R4 fused kernel) if ws_size < 2 MB ----
constexpr int ROWS = 2, BCH = 8;
__global__ __launch_bounds__(256)
void mask_apply_fused(const float* __restrict__ x, const float* __restrict__ trand,
                      const float* __restrict__ frand, const int* __restrict__ tstart,
                      const int* __restrict__ fstart, float* __restrict__ out) {
    __shared__ int flagw[ROWS * WC / 4];
    __shared__ int ts_s[B_], fs_s[B_];
    unsigned char* flags = (unsigned char*)flagw;
    const int t = threadIdx.x, h0 = blockIdx.x * ROWS, b0 = blockIdx.y * BCH;
    flagw[2 * t] = 0; flagw[2 * t + 1] = 0;
    if (t < B_) { ts_s[t] = tstart[t]; fs_s[t] = fstart[t]; }
    __syncthreads();
    for (int b = 0; b < B_; ++b) {
        int ts = ts_s[b];
#pragma unroll
        for (int r = 0; r < ROWS; ++r) {
            int l = h0 + r - ts;
            if ((unsigned)l < (unsigned)L_) {
                const float* row = trand + (b * L_ + l) * WC;
#pragma unroll
                for (int k = 0; k < 4; ++k)
                    if (row[t * 4 + k] < 0.15f) flags[r * WC + t * 4 + k] = 1;
            }
        }
    }
    {
        int bsub = t >> 5, lane = t & 31, l = lane >> 2, c = lane & 3;
        for (int bb = 0; bb < B_; bb += 8) {
            int b = bb + bsub, fs = fs_s[b];
#pragma unroll
            for (int r = 0; r < ROWS; ++r) {
                float vf = frand[(b * H_ + h0 + r) * (L_ * C_) + l * C_ + c];
                if (vf < 0.15f) flags[r * WC + (fs + l) * C_ + c] = 1;
            }
        }
    }
    __syncthreads();
    const unsigned fw0 = (unsigned)flagw[t], fw1 = (unsigned)flagw[256 + t];
    for (int bi = 0; bi < BCH; ++bi) {
        int base = (b0 + bi) * HWC + h0 * WC;
        float4 v0 = ((const float4*)(x + base))[t];
        float4 v1 = ((const float4*)(x + base + WC))[t];
        if (fw0 & 0xffu)       v0.x = 0.f;
        if (fw0 & 0xff00u)     v0.y = 0.f;
        if (fw0 & 0xff0000u)   v0.z = 0.f;
        if (fw0 & 0xff000000u) v0.w = 0.f;
        if (fw1 & 0xffu)       v1.x = 0.f;
        if (fw1 & 0xff00u)     v1.y = 0.f;
        if (fw1 & 0xff0000u)   v1.z = 0.f;
        if (fw1 & 0xff000000u) v1.w = 0.f;
        ((float4*)(out + base))[t]      = v0;
        ((float4*)(out + base + WC))[t] = v1;
    }
}

extern "C" void kernel_launch(void* const* d_in, const int* in_sizes, int n_in,
                              void* d_out, int out_size, void* d_ws, size_t ws_size,
                              hipStream_t stream) {
    const float* x  = (const float*)d_in[0];
    const float* tr = (const float*)d_in[1];
    const float* fr = (const float*)d_in[2];
    const int*   ts = (const int*)d_in[3];
    const int*   fs = (const int*)d_in[4];
    float* out = (float*)d_out;

    if (ws_size >= (size_t)HWC * sizeof(float)) {
        float* mask = (float*)d_ws;                 // d_ws re-poisoned each call;
        build_mask<<<H_, 256, 0, stream>>>(tr, fr, ts, fs, mask);  // fully rewritten here
        apply_mask<<<(int)(N4 / 1024), 256, 0, stream>>>(
            (const float4*)x, (const float4*)mask, (float4*)out);
    } else {
        dim3 grid(H_ / ROWS, B_ / BCH);
        mask_apply_fused<<<grid, 256, 0, stream>>>(x, tr, fr, ts, fs, out);
    }
}

// Round 7
// 245.474 us; speedup vs baseline: 1.0788x; 1.0249x over previous
//
#include <hip/hip_runtime.h>

// out[b,h,w,c] = x[b,h,w,c] * mask[h,w,c], ALL FLOAT32.
// mask[h,w,c]=0 iff ANY batch's time strip (ts[b]<=h<ts[b]+8, trand[b,h-ts,w,c]<0.15)
//           or ANY batch's freq strip (fs[b]<=w<fs[b]+8, frand[b,h,w-fs,c]<0.15) hits.
//
// R6 failed to compile only: __builtin_nontemporal_store needs a NATIVE vector
// type, not HIP's float4 class. R7 = R6 with ext_vector_type for NT stores.
constexpr int B_ = 64, H_ = 512, W_ = 256, C_ = 4, L_ = 8;
constexpr int WC     = W_ * C_;        // 1024
constexpr int HWC    = H_ * WC;        // 524288 flag bytes / floats per batch
constexpr int HWC4   = HWC / 4;        // 131072 flag dwords
constexpr int N_TIME = B_ * L_ * WC;   // 524288
constexpr int N_FREQ = B_ * H_ * L_ * C_;  // 1048576
constexpr long long N4 = 8388608LL;    // float4 count in x/out

typedef float floatx4 __attribute__((ext_vector_type(4)));  // native vec for NT store

// ---- kernel 1: scatter. One thread per rand element; writes flag=1 on hit.
__global__ __launch_bounds__(256)
void scatter_mask(const float* __restrict__ trand, const float* __restrict__ frand,
                  const int* __restrict__ tstart, const int* __restrict__ fstart,
                  unsigned char* __restrict__ flags) {
    int tid = blockIdx.x * 256 + threadIdx.x;
    if (tid < N_TIME) {
        // trand [B,L,W,C], linear == tid
        if (trand[tid] < 0.15f) {
            int wc = tid & (WC - 1);               // w*4+c
            int l  = (tid >> 10) & (L_ - 1);
            int b  = tid >> 13;
            int h  = tstart[b] + l;                // in [0,H) since ts<=H-8
            flags[h * WC + wc] = 1;
        }
    } else {
        int j = tid - N_TIME;                      // frand [B,H,L,C], linear == j
        if (frand[j] < 0.15f) {
            int c = j & (C_ - 1);
            int l = (j >> 2) & (L_ - 1);
            int h = (j >> 5) & (H_ - 1);
            int b = j >> 14;
            int w = fstart[b] + l;                 // in [0,W)
            flags[h * WC + w * C_ + c] = 1;
        }
    }
}

// ---- kernel 2: streaming apply. 4 independent float4 per thread, no LDS,
// no barriers; flag dwords come from the 512KB L2-resident table.
__global__ __launch_bounds__(256)
void apply_mask(const floatx4* __restrict__ x4,
                const unsigned int* __restrict__ flag32,
                floatx4* __restrict__ out4) {
    const int base = blockIdx.x * 1024 + threadIdx.x;
    floatx4 a0 = x4[base];
    floatx4 a1 = x4[base + 256];
    floatx4 a2 = x4[base + 512];
    floatx4 a3 = x4[base + 768];
    unsigned f0 = flag32[ base         & (HWC4 - 1)];
    unsigned f1 = flag32[(base +  256) & (HWC4 - 1)];
    unsigned f2 = flag32[(base +  512) & (HWC4 - 1)];
    unsigned f3 = flag32[(base +  768) & (HWC4 - 1)];
    if (f0 & 0xffu) a0.x = 0.f;  if (f0 & 0xff00u) a0.y = 0.f;
    if (f0 & 0xff0000u) a0.z = 0.f;  if (f0 & 0xff000000u) a0.w = 0.f;
    if (f1 & 0xffu) a1.x = 0.f;  if (f1 & 0xff00u) a1.y = 0.f;
    if (f1 & 0xff0000u) a1.z = 0.f;  if (f1 & 0xff000000u) a1.w = 0.f;
    if (f2 & 0xffu) a2.x = 0.f;  if (f2 & 0xff00u) a2.y = 0.f;
    if (f2 & 0xff0000u) a2.z = 0.f;  if (f2 & 0xff000000u) a2.w = 0.f;
    if (f3 & 0xffu) a3.x = 0.f;  if (f3 & 0xff00u) a3.y = 0.f;
    if (f3 & 0xff0000u) a3.z = 0.f;  if (f3 & 0xff000000u) a3.w = 0.f;
    __builtin_nontemporal_store(a0, &out4[base]);        // out is write-only:
    __builtin_nontemporal_store(a1, &out4[base + 256]);  // don't evict x/flags
    __builtin_nontemporal_store(a2, &out4[base + 512]);
    __builtin_nontemporal_store(a3, &out4[base + 768]);
}

// ---- fallback (proven R4 fused kernel) if ws_size too small ----
constexpr int ROWS = 2, BCH = 8;
__global__ __launch_bounds__(256)
void mask_apply_fused(const float* __restrict__ x, const float* __restrict__ trand,
                      const float* __restrict__ frand, const int* __restrict__ tstart,
                      const int* __restrict__ fstart, float* __restrict__ out) {
    __shared__ int flagw[ROWS * WC / 4];
    __shared__ int ts_s[B_], fs_s[B_];
    unsigned char* flags = (unsigned char*)flagw;
    const int t = threadIdx.x, h0 = blockIdx.x * ROWS, b0 = blockIdx.y * BCH;
    flagw[2 * t] = 0; flagw[2 * t + 1] = 0;
    if (t < B_) { ts_s[t] = tstart[t]; fs_s[t] = fstart[t]; }
    __syncthreads();
    for (int b = 0; b < B_; ++b) {
        int ts = ts_s[b];
#pragma unroll
        for (int r = 0; r < ROWS; ++r) {
            int l = h0 + r - ts;
            if ((unsigned)l < (unsigned)L_) {
                const float* row = trand + (b * L_ + l) * WC;
#pragma unroll
                for (int k = 0; k < 4; ++k)
                    if (row[t * 4 + k] < 0.15f) flags[r * WC + t * 4 + k] = 1;
            }
        }
    }
    {
        int bsub = t >> 5, lane = t & 31, l = lane >> 2, c = lane & 3;
        for (int bb = 0; bb < B_; bb += 8) {
            int b = bb + bsub, fs = fs_s[b];
#pragma unroll
            for (int r = 0; r < ROWS; ++r) {
                float vf = frand[(b * H_ + h0 + r) * (L_ * C_) + l * C_ + c];
                if (vf < 0.15f) flags[r * WC + (fs + l) * C_ + c] = 1;
            }
        }
    }
    __syncthreads();
    const unsigned fw0 = (unsigned)flagw[t], fw1 = (unsigned)flagw[256 + t];
    for (int bi = 0; bi < BCH; ++bi) {
        int base = (b0 + bi) * HWC + h0 * WC;
        float4 v0 = ((const float4*)(x + base))[t];
        float4 v1 = ((const float4*)(x + base + WC))[t];
        if (fw0 & 0xffu)       v0.x = 0.f;
        if (fw0 & 0xff00u)     v0.y = 0.f;
        if (fw0 & 0xff0000u)   v0.z = 0.f;
        if (fw0 & 0xff000000u) v0.w = 0.f;
        if (fw1 & 0xffu)       v1.x = 0.f;
        if (fw1 & 0xff00u)     v1.y = 0.f;
        if (fw1 & 0xff0000u)   v1.z = 0.f;
        if (fw1 & 0xff000000u) v1.w = 0.f;
        ((float4*)(out + base))[t]      = v0;
        ((float4*)(out + base + WC))[t] = v1;
    }
}

extern "C" void kernel_launch(void* const* d_in, const int* in_sizes, int n_in,
                              void* d_out, int out_size, void* d_ws, size_t ws_size,
                              hipStream_t stream) {
    const float* x  = (const float*)d_in[0];
    const float* tr = (const float*)d_in[1];
    const float* fr = (const float*)d_in[2];
    const int*   ts = (const int*)d_in[3];
    const int*   fs = (const int*)d_in[4];
    float* out = (float*)d_out;

    if (ws_size >= (size_t)HWC) {
        unsigned char* flags = (unsigned char*)d_ws;   // 512 KB, re-poisoned: clear
        (void)hipMemsetAsync(flags, 0, HWC, stream);
        scatter_mask<<<(N_TIME + N_FREQ) / 256, 256, 0, stream>>>(tr, fr, ts, fs, flags);
        apply_mask<<<(int)(N4 / 1024), 256, 0, stream>>>(
            (const floatx4*)x, (const unsigned int*)flags, (floatx4*)out);
    } else {
        dim3 grid(H_ / ROWS, B_ / BCH);
        mask_apply_fused<<<grid, 256, 0, stream>>>(x, tr, fr, ts, fs, out);
    }
}